// Round 1
// baseline (1381.480 us; speedup 1.0000x reference)
//
#include <hip/hip_runtime.h>
#include <stdint.h>

// ---- Problem constants -------------------------------------------------
#define DIM   1536
#define NQ    6272      // 8 * 28 * 28 queries
#define NB    50000     // bank rows
#define NBP   50048     // padded to multiple of 128 (391 * 128)
#define MT    49        // NQ / 128
#define NT    391       // NBP / 128
#define GRID_GEMM (MT * NT)
#define NPIX  (8 * 224 * 224)

typedef __bf16 bf16x8 __attribute__((ext_vector_type(8)));
typedef float  f32x4  __attribute__((ext_vector_type(4)));

__device__ inline unsigned short f2bf(float f) {
  uint32_t u = __float_as_uint(f);
  u += 0x7FFFu + ((u >> 16) & 1u);   // RNE
  return (unsigned short)(u >> 16);
}

__device__ inline void gll16(const unsigned short* g, unsigned short* l) {
  __builtin_amdgcn_global_load_lds(
      (const __attribute__((address_space(1))) uint32_t*)g,
      (__attribute__((address_space(3))) uint32_t*)l, 16, 0, 0);
}

// ---- init: minbits = +inf, image scores = 0 ---------------------------
__global__ void init_kernel(uint32_t* __restrict__ minbits, float* __restrict__ out_scores) {
  int i = blockIdx.x * 256 + threadIdx.x;
  if (i < NQ) minbits[i] = 0x7F800000u;   // +inf
  if (i < 8)  out_scores[i] = 0.0f;
}

// ---- fp32 -> bf16 row conversion + fp32 row norms ---------------------
// one wave per row; 1536 = 64 lanes * 6 float4
__global__ void conv_rows(const float* __restrict__ src, unsigned short* __restrict__ dst,
                          float* __restrict__ norms, int nsrc, int ndst) {
  int row  = blockIdx.x * 4 + (threadIdx.x >> 6);
  int lane = threadIdx.x & 63;
  if (row >= ndst) return;
  unsigned short* drow = dst + (size_t)row * DIM;
  if (row < nsrc) {
    const float4* s = (const float4*)(src + (size_t)row * DIM);
    float ns = 0.f;
#pragma unroll
    for (int i = 0; i < 6; ++i) {
      float4 v = s[lane + 64 * i];
      ns += v.x * v.x + v.y * v.y + v.z * v.z + v.w * v.w;
      ushort4 o;
      o.x = f2bf(v.x); o.y = f2bf(v.y); o.z = f2bf(v.z); o.w = f2bf(v.w);
      *(ushort4*)(drow + (lane + 64 * i) * 4) = o;
    }
#pragma unroll
    for (int off = 32; off >= 1; off >>= 1) ns += __shfl_xor(ns, off);
    if (lane == 0) norms[row] = ns;
  } else {
    ushort4 z = {0, 0, 0, 0};
#pragma unroll
    for (int i = 0; i < 6; ++i) *(ushort4*)(drow + (lane + 64 * i) * 4) = z;
    if (lane == 0) norms[row] = 1e30f;   // pad rows never win the min
  }
}

// ---- fused GEMM + column-min (m97 structure) --------------------------
// 128x128 tile, BK=32, 256 threads = 4 waves in 2x2, 4x4 16x16x32 frags/wave
__global__ __launch_bounds__(256)
void gemm_min(const unsigned short* __restrict__ fA, const unsigned short* __restrict__ bB,
              const float* __restrict__ bn, uint32_t* __restrict__ minbits) {
  __shared__ unsigned short As[128 * 32];   // 8 KB
  __shared__ unsigned short Bs[128 * 32];   // 8 KB

  int bid = blockIdx.x;
  // bijective XCD swizzle (m204): contiguous swz chunk per XCD
  const int nwg = GRID_GEMM;
  const int qch = nwg >> 3, rch = nwg & 7;
  int xcd = bid & 7, loc = bid >> 3;
  int swz = (xcd < rch ? xcd * (qch + 1) : rch * (qch + 1) + (xcd - rch) * qch) + loc;
  int mt = swz % MT;            // M fast -> consecutive blocks share bank tile (L2 reuse)
  int nt = swz / MT;

  int tid  = threadIdx.x;
  int wave = tid >> 6, lane = tid & 63;
  int wm = wave >> 1, wn = wave & 1;
  int lr = lane & 15, lk = (lane >> 4) * 8;

  const unsigned short* gA = fA + (size_t)mt * 128 * DIM;
  const unsigned short* gB = bB + (size_t)nt * 128 * DIM;
  int r4 = tid >> 2;            // 0..63: row within 64-row half
  int c8 = (tid & 3) * 8;       // 8-elem column chunk within BK=32

  f32x4 acc[4][4] = {};

  for (int kt = 0; kt < DIM; kt += 32) {
    // stage A(128x32) and B(128x32) via direct-to-LDS 16B loads
    gll16(gA + (size_t)r4 * DIM + kt + c8,        As + tid * 8);
    gll16(gA + (size_t)(64 + r4) * DIM + kt + c8, As + 2048 + tid * 8);
    gll16(gB + (size_t)r4 * DIM + kt + c8,        Bs + tid * 8);
    gll16(gB + (size_t)(64 + r4) * DIM + kt + c8, Bs + 2048 + tid * 8);
    __syncthreads();            // compiler drains vmcnt before s_barrier

    bf16x8 a[4], b[4];
#pragma unroll
    for (int mi = 0; mi < 4; ++mi)
      a[mi] = *(const bf16x8*)&As[(wm * 64 + mi * 16 + lr) * 32 + lk];
#pragma unroll
    for (int ni = 0; ni < 4; ++ni)
      b[ni] = *(const bf16x8*)&Bs[(wn * 64 + ni * 16 + lr) * 32 + lk];
#pragma unroll
    for (int mi = 0; mi < 4; ++mi)
#pragma unroll
      for (int ni = 0; ni < 4; ++ni)
        acc[mi][ni] = __builtin_amdgcn_mfma_f32_16x16x32_bf16(a[mi], b[ni], acc[mi][ni], 0, 0, 0);
    __syncthreads();
  }

  // epilogue: per-row min over this tile's 128 columns of (bn - 2*dot)
  float bnv[4];
#pragma unroll
  for (int ni = 0; ni < 4; ++ni)
    bnv[ni] = bn[nt * 128 + wn * 64 + ni * 16 + lr];
  int qbase = mt * 128 + wm * 64;
#pragma unroll
  for (int mi = 0; mi < 4; ++mi) {
#pragma unroll
    for (int r = 0; r < 4; ++r) {
      float v = bnv[0] - 2.0f * acc[mi][0][r];
      v = fminf(v, bnv[1] - 2.0f * acc[mi][1][r]);
      v = fminf(v, bnv[2] - 2.0f * acc[mi][2][r]);
      v = fminf(v, bnv[3] - 2.0f * acc[mi][3][r]);
      // C/D layout: col = lane&15, row = (lane>>4)*4 + r  (m89/m91 verified)
      v = fminf(v, __shfl_xor(v, 1));
      v = fminf(v, __shfl_xor(v, 2));
      v = fminf(v, __shfl_xor(v, 4));
      v = fminf(v, __shfl_xor(v, 8));
      if (lr == 0) {
        int q = qbase + mi * 16 + (lane >> 4) * 4 + r;
        atomicMin(&minbits[q], __float_as_uint(v));  // positive floats: uint order == float order
      }
    }
  }
}

// ---- patch scores + per-image max -------------------------------------
__global__ void scores_kernel(const uint32_t* __restrict__ minbits, const float* __restrict__ qn,
                              float* __restrict__ ps, float* __restrict__ img) {
  int q = blockIdx.x * 256 + threadIdx.x;
  if (q >= NQ) return;
  float s = __uint_as_float(minbits[q]) + qn[q];
  ps[q] = s;
  atomicMax((uint32_t*)&img[q / 784], __float_as_uint(s));  // scores > 0
}

// ---- bilinear 28x28 -> 224x224 (half-pixel centers, edge clamp) -------
__global__ void resize_kernel(const float* __restrict__ ps, float* __restrict__ masks) {
  int idx = blockIdx.x * 256 + threadIdx.x;
  if (idx >= NPIX) return;
  int b   = idx / (224 * 224);
  int rem = idx - b * (224 * 224);
  int oy  = rem / 224;
  int ox  = rem - oy * 224;
  float sy = (oy + 0.5f) * 0.125f - 0.5f;
  float sx = (ox + 0.5f) * 0.125f - 0.5f;
  float fy0 = floorf(sy), fx0 = floorf(sx);
  int y0 = (int)fy0, x0 = (int)fx0;
  float fy = sy - fy0, fx = sx - fx0;
  int y0c = min(max(y0, 0), 27),     y1c = min(max(y0 + 1, 0), 27);
  int x0c = min(max(x0, 0), 27),     x1c = min(max(x0 + 1, 0), 27);
  const float* p = ps + b * 784;
  float top = p[y0c * 28 + x0c] * (1.f - fx) + p[y0c * 28 + x1c] * fx;
  float bot = p[y1c * 28 + x0c] * (1.f - fx) + p[y1c * 28 + x1c] * fx;
  masks[idx] = top * (1.f - fy) + bot * fy;
}

// ---- host launch -------------------------------------------------------
extern "C" void kernel_launch(void* const* d_in, const int* in_sizes, int n_in,
                              void* d_out, int out_size, void* d_ws, size_t ws_size,
                              hipStream_t stream) {
  const float* features = (const float*)d_in[0];   // [6272, 1536]
  const float* bank     = (const float*)d_in[1];   // [50000, 1536]
  // d_in[2] = batchsize (8), hardcoded via constants

  char* ws = (char*)d_ws;
  size_t off = 0;
  unsigned short* bankB = (unsigned short*)(ws + off); off += (size_t)NBP * DIM * 2;  // 153.7 MB
  unsigned short* featB = (unsigned short*)(ws + off); off += (size_t)NQ  * DIM * 2;  // 19.3 MB
  float*    bn      = (float*)(ws + off);    off += (size_t)NBP * 4;
  float*    qn      = (float*)(ws + off);    off += (size_t)NQ * 4;
  uint32_t* minbits = (uint32_t*)(ws + off); off += (size_t)NQ * 4;
  float*    ps      = (float*)(ws + off);    off += (size_t)NQ * 4;

  float* out_scores = (float*)d_out;       // [8]
  float* masks      = out_scores + 8;      // [8,224,224]

  hipLaunchKernelGGL(init_kernel, dim3(25), dim3(256), 0, stream, minbits, out_scores);
  hipLaunchKernelGGL(conv_rows, dim3(NBP / 4), dim3(256), 0, stream, bank, bankB, bn, NB, NBP);
  hipLaunchKernelGGL(conv_rows, dim3(NQ / 4), dim3(256), 0, stream, features, featB, qn, NQ, NQ);
  hipLaunchKernelGGL(gemm_min, dim3(GRID_GEMM), dim3(256), 0, stream, featB, bankB, bn, minbits);
  hipLaunchKernelGGL(scores_kernel, dim3(25), dim3(256), 0, stream, minbits, qn, ps, out_scores);
  hipLaunchKernelGGL(resize_kernel, dim3((NPIX + 255) / 256), dim3(256), 0, stream, ps, masks);
}

// Round 2
// 1139.869 us; speedup vs baseline: 1.2120x; 1.2120x over previous
//
#include <hip/hip_runtime.h>
#include <stdint.h>

// ---- Problem constants -------------------------------------------------
#define DIM   1536
#define NQ    6272      // 8 * 28 * 28 queries
#define NQP   6400      // padded to 25 * 256
#define NB    50000     // bank rows
#define NBP2  50176     // padded to 196 * 256
#define MT2   25
#define NT2   196
#define GRID2 (MT2 * NT2)
#define NKT   24        // 1536 / 64 K-tiles
#define NPIX  (8 * 224 * 224)

typedef __bf16 bf16x8 __attribute__((ext_vector_type(8)));
typedef float  f32x4  __attribute__((ext_vector_type(4)));

__device__ inline unsigned short f2bf(float f) {
  uint32_t u = __float_as_uint(f);
  u += 0x7FFFu + ((u >> 16) & 1u);   // RNE
  return (unsigned short)(u >> 16);
}

__device__ inline void gll16(const unsigned short* g, unsigned short* l) {
  __builtin_amdgcn_global_load_lds(
      (const __attribute__((address_space(1))) uint32_t*)g,
      (__attribute__((address_space(3))) uint32_t*)l, 16, 0, 0);
}

// ---- init: minbits = +inf, image scores = 0 ---------------------------
__global__ void init_kernel(uint32_t* __restrict__ minbits, float* __restrict__ out_scores) {
  int i = blockIdx.x * 256 + threadIdx.x;
  if (i < NQP) minbits[i] = 0x7F800000u;   // +inf
  if (i < 8)   out_scores[i] = 0.0f;
}

// ---- fp32 -> bf16 row conversion + fp32 row norms ---------------------
__global__ void conv_rows(const float* __restrict__ src, unsigned short* __restrict__ dst,
                          float* __restrict__ norms, int nsrc, int ndst) {
  int row  = blockIdx.x * 4 + (threadIdx.x >> 6);
  int lane = threadIdx.x & 63;
  if (row >= ndst) return;
  unsigned short* drow = dst + (size_t)row * DIM;
  if (row < nsrc) {
    const float4* s = (const float4*)(src + (size_t)row * DIM);
    float ns = 0.f;
#pragma unroll
    for (int i = 0; i < 6; ++i) {
      float4 v = s[lane + 64 * i];
      ns += v.x * v.x + v.y * v.y + v.z * v.z + v.w * v.w;
      ushort4 o;
      o.x = f2bf(v.x); o.y = f2bf(v.y); o.z = f2bf(v.z); o.w = f2bf(v.w);
      *(ushort4*)(drow + (lane + 64 * i) * 4) = o;
    }
#pragma unroll
    for (int off = 32; off >= 1; off >>= 1) ns += __shfl_xor(ns, off);
    if (lane == 0) norms[row] = ns;
  } else {
    ushort4 z = {0, 0, 0, 0};
#pragma unroll
    for (int i = 0; i < 6; ++i) *(ushort4*)(drow + (lane + 64 * i) * 4) = z;
    if (lane == 0) norms[row] = 1e30f;   // pad rows never win the min
  }
}

// ---- fused 256x256 8-phase GEMM + column-min --------------------------
// BM=BN=256, BK=64, 512 thr = 8 waves (2M x 4N), per-wave 128x64 out.
// LDS 128 KiB: [buf][half][128x64] bf16 for A and B, XOR-swizzled slot^=row&7.
#define BAR   asm volatile("s_barrier" ::: "memory")
#define LGKM0 do { asm volatile("s_waitcnt lgkmcnt(0)" ::: "memory"); __builtin_amdgcn_sched_barrier(0); } while(0)
#define VM6   asm volatile("s_waitcnt vmcnt(6)" ::: "memory")
#define VM0   asm volatile("s_waitcnt vmcnt(0)" ::: "memory")
#define PHI   __builtin_amdgcn_s_setprio(1)
#define PLO   __builtin_amdgcn_s_setprio(0)

#define READ_A(arr, bufI, mB) do { \
  _Pragma("unroll") for (int m_ = 0; m_ < 4; ++m_) \
  _Pragma("unroll") for (int k_ = 0; k_ < 2; ++k_) \
    arr[m_][k_] = *(const bf16x8*)&sA[bufI][wm][(((mB) + m_) * 16 + lr) * 64 + ((k_ * 32 + lk8) ^ lswz)]; \
} while(0)

#define READ_B(bufI) do { \
  _Pragma("unroll") for (int n_ = 0; n_ < 4; ++n_) \
  _Pragma("unroll") for (int k_ = 0; k_ < 2; ++k_) \
    bf[n_][k_] = *(const bf16x8*)&sB[bufI][bh][(bq * 64 + n_ * 16 + lr) * 64 + ((k_ * 32 + lk8) ^ lswz)]; \
} while(0)

#define MFMA2(mB, arr, aB) do { \
  _Pragma("unroll") for (int m_ = 0; m_ < 2; ++m_) \
  _Pragma("unroll") for (int n_ = 0; n_ < 4; ++n_) \
  _Pragma("unroll") for (int k_ = 0; k_ < 2; ++k_) \
    acc[(mB) + m_][n_] = __builtin_amdgcn_mfma_f32_16x16x32_bf16(arr[(aB) + m_][k_], bf[n_][k_], acc[(mB) + m_][n_], 0, 0, 0); \
} while(0)

#define STAGE_A(bufI, hI, ktc) do { \
  const unsigned short* _g = gA + (size_t)((hI) * 128 + srow) * DIM + (ktc) + scol; \
  gll16(_g,                     &sA[bufI][hI][sdst]); \
  gll16(_g + (size_t)64 * DIM,  &sA[bufI][hI][4096 + sdst]); \
} while(0)

#define STAGE_B(bufI, hI, ktc) do { \
  const unsigned short* _g = gB + (size_t)((hI) * 128 + srow) * DIM + (ktc) + scol; \
  gll16(_g,                     &sB[bufI][hI][sdst]); \
  gll16(_g + (size_t)64 * DIM,  &sB[bufI][hI][4096 + sdst]); \
} while(0)

__global__ __launch_bounds__(512, 2)
void gemm_min8(const unsigned short* __restrict__ fA, const unsigned short* __restrict__ bB,
               const float* __restrict__ bn, uint32_t* __restrict__ minbits) {
  __shared__ unsigned short sA[2][2][8192];   // 64 KiB
  __shared__ unsigned short sB[2][2][8192];   // 64 KiB

  const int nwg = GRID2;
  int bid = blockIdx.x;
  const int qch = nwg >> 3, rch = nwg & 7;
  int xcd = bid & 7, loc = bid >> 3;
  int swz = (xcd < rch ? xcd * (qch + 1) : rch * (qch + 1) + (xcd - rch) * qch) + loc;
  int mt = swz % MT2;            // M-fast: consecutive blocks share the B (bank) panel
  int nt = swz / MT2;

  int tid = threadIdx.x;
  int lane = tid & 63, wave = tid >> 6;
  int wm = wave >> 2, wn = wave & 3, bq = wn & 1, bh = wn >> 1;
  int lr = lane & 15, lk8 = (lane >> 4) * 8;
  int lswz = (lane & 7) << 3;    // XOR on 16B-slot bits (ushort units)

  const unsigned short* gA = fA + (size_t)(mt * 256) * DIM;
  const unsigned short* gB = bB + (size_t)(nt * 256) * DIM;

  int srow = tid >> 3;                                    // 0..63
  int scol = ((tid & 7) * 8) ^ (((tid >> 3) & 7) << 3);   // pre-swizzled source col (bf16)
  int sdst = tid * 8;                                     // linear LDS dest (ushort)

  f32x4 acc[8][4] = {};
  bf16x8 a03[4][2], a47[4][2], bf[4][2];

  // prologue: tile0 full into buf0; tile1 B0,B1,A0 into buf1 (3 halves stay in flight)
  STAGE_A(0, 0, 0); STAGE_A(0, 1, 0); STAGE_B(0, 0, 0); STAGE_B(0, 1, 0);
  STAGE_B(1, 0, 64); STAGE_B(1, 1, 64); STAGE_A(1, 0, 64);
  VM6; BAR;

#pragma unroll 1
  for (int i = 0; i < NKT / 2 - 1; ++i) {
    int kt = i * 128;             // tile 2i col base
    // ph1: compute buf0 mi0-1; stage buf1.A1 (tile 2i+1)
    READ_A(a03, 0, 0); READ_B(0);
    STAGE_A(1, 1, kt + 64);
    BAR; LGKM0; PHI; MFMA2(0, a03, 0); PLO; BAR;
    // ph2: stage buf0.B0 (tile 2i+2)
    STAGE_B(0, 0, kt + 128);
    BAR; PHI; MFMA2(2, a03, 2); PLO; BAR;
    // ph3: read A mi4-7; stage buf0.B1
    READ_A(a47, 0, 4);
    STAGE_B(0, 1, kt + 128);
    BAR; LGKM0; PHI; MFMA2(4, a47, 0); PLO; BAR;
    // ph4: stage buf0.A0; K-tile boundary wait
    STAGE_A(0, 0, kt + 128);
    BAR; PHI; MFMA2(6, a47, 2); PLO; VM6; BAR;
    // ph5: compute buf1 mi0-1; stage buf0.A1
    READ_A(a03, 1, 0); READ_B(1);
    STAGE_A(0, 1, kt + 128);
    BAR; LGKM0; PHI; MFMA2(0, a03, 0); PLO; BAR;
    // ph6: stage buf1.B0 (tile 2i+3)
    STAGE_B(1, 0, kt + 192);
    BAR; PHI; MFMA2(2, a03, 2); PLO; BAR;
    // ph7: read A mi4-7; stage buf1.B1
    READ_A(a47, 1, 4);
    STAGE_B(1, 1, kt + 192);
    BAR; LGKM0; PHI; MFMA2(4, a47, 0); PLO; BAR;
    // ph8: stage buf1.A0; K-tile boundary wait
    STAGE_A(1, 0, kt + 192);
    BAR; PHI; MFMA2(6, a47, 2); PLO; VM6; BAR;
  }

  // epilogue iteration: tiles 22 (buf0) and 23 (buf1); no new prefetch
  {
    int kt = (NKT / 2 - 1) * 128;
    READ_A(a03, 0, 0); READ_B(0);
    STAGE_A(1, 1, kt + 64);       // last half of tile 23
    BAR; LGKM0; PHI; MFMA2(0, a03, 0); PLO; BAR;
    BAR; PHI; MFMA2(2, a03, 2); PLO; BAR;
    READ_A(a47, 0, 4);
    BAR; LGKM0; PHI; MFMA2(4, a47, 0); PLO; BAR;
    BAR; PHI; MFMA2(6, a47, 2); PLO; VM0; BAR;   // drain: tile 23 fully landed
    READ_A(a03, 1, 0); READ_B(1);
    BAR; LGKM0; PHI; MFMA2(0, a03, 0); PLO; BAR;
    BAR; PHI; MFMA2(2, a03, 2); PLO; BAR;
    READ_A(a47, 1, 4);
    BAR; LGKM0; PHI; MFMA2(4, a47, 0); PLO; BAR;
    BAR; PHI; MFMA2(6, a47, 2); PLO; BAR;
  }

  // epilogue: per-row min over this tile's 256 columns of (bn - 2*dot)
  float bnv[4];
#pragma unroll
  for (int n_ = 0; n_ < 4; ++n_)
    bnv[n_] = bn[nt * 256 + wn * 64 + n_ * 16 + lr];
  int qbase = mt * 256 + wm * 128;
#pragma unroll
  for (int m_ = 0; m_ < 8; ++m_) {
#pragma unroll
    for (int r = 0; r < 4; ++r) {
      float v = bnv[0] - 2.0f * acc[m_][0][r];
      v = fminf(v, bnv[1] - 2.0f * acc[m_][1][r]);
      v = fminf(v, bnv[2] - 2.0f * acc[m_][2][r]);
      v = fminf(v, bnv[3] - 2.0f * acc[m_][3][r]);
      // C/D layout: col = lane&15, row = (lane>>4)*4 + r
      v = fminf(v, __shfl_xor(v, 1));
      v = fminf(v, __shfl_xor(v, 2));
      v = fminf(v, __shfl_xor(v, 4));
      v = fminf(v, __shfl_xor(v, 8));
      if (lr == 0) {
        int q = qbase + m_ * 16 + (lane >> 4) * 4 + r;
        atomicMin(&minbits[q], __float_as_uint(v));  // positive floats: uint order == float order
      }
    }
  }
}

// ---- patch scores + per-image max -------------------------------------
__global__ void scores_kernel(const uint32_t* __restrict__ minbits, const float* __restrict__ qn,
                              float* __restrict__ ps, float* __restrict__ img) {
  int q = blockIdx.x * 256 + threadIdx.x;
  if (q >= NQ) return;
  float s = __uint_as_float(minbits[q]) + qn[q];
  ps[q] = s;
  atomicMax((uint32_t*)&img[q / 784], __float_as_uint(s));  // scores > 0
}

// ---- bilinear 28x28 -> 224x224 (half-pixel centers, edge clamp) -------
__global__ void resize_kernel(const float* __restrict__ ps, float* __restrict__ masks) {
  int idx = blockIdx.x * 256 + threadIdx.x;
  if (idx >= NPIX) return;
  int b   = idx / (224 * 224);
  int rem = idx - b * (224 * 224);
  int oy  = rem / 224;
  int ox  = rem - oy * 224;
  float sy = (oy + 0.5f) * 0.125f - 0.5f;
  float sx = (ox + 0.5f) * 0.125f - 0.5f;
  float fy0 = floorf(sy), fx0 = floorf(sx);
  int y0 = (int)fy0, x0 = (int)fx0;
  float fy = sy - fy0, fx = sx - fx0;
  int y0c = min(max(y0, 0), 27),     y1c = min(max(y0 + 1, 0), 27);
  int x0c = min(max(x0, 0), 27),     x1c = min(max(x0 + 1, 0), 27);
  const float* p = ps + b * 784;
  float top = p[y0c * 28 + x0c] * (1.f - fx) + p[y0c * 28 + x1c] * fx;
  float bot = p[y1c * 28 + x0c] * (1.f - fx) + p[y1c * 28 + x1c] * fx;
  masks[idx] = top * (1.f - fy) + bot * fy;
}

// ---- host launch -------------------------------------------------------
extern "C" void kernel_launch(void* const* d_in, const int* in_sizes, int n_in,
                              void* d_out, int out_size, void* d_ws, size_t ws_size,
                              hipStream_t stream) {
  const float* features = (const float*)d_in[0];   // [6272, 1536]
  const float* bank     = (const float*)d_in[1];   // [50000, 1536]

  char* ws = (char*)d_ws;
  size_t off = 0;
  unsigned short* bankB = (unsigned short*)(ws + off); off += (size_t)NBP2 * DIM * 2;  // 154.1 MB
  unsigned short* featB = (unsigned short*)(ws + off); off += (size_t)NQP * DIM * 2;   // 19.7 MB
  float*    bn      = (float*)(ws + off);    off += (size_t)NBP2 * 4;
  float*    qn      = (float*)(ws + off);    off += (size_t)NQP * 4;
  uint32_t* minbits = (uint32_t*)(ws + off); off += (size_t)NQP * 4;
  float*    ps      = (float*)(ws + off);    off += (size_t)NQ * 4;

  float* out_scores = (float*)d_out;       // [8]
  float* masks      = out_scores + 8;      // [8,224,224]

  hipLaunchKernelGGL(init_kernel, dim3(25), dim3(256), 0, stream, minbits, out_scores);
  hipLaunchKernelGGL(conv_rows, dim3(NBP2 / 4), dim3(256), 0, stream, bank, bankB, bn, NB, NBP2);
  hipLaunchKernelGGL(conv_rows, dim3(NQP / 4), dim3(256), 0, stream, features, featB, qn, NQ, NQP);
  hipLaunchKernelGGL(gemm_min8, dim3(GRID2), dim3(512), 0, stream, featB, bankB, bn, minbits);
  hipLaunchKernelGGL(scores_kernel, dim3(25), dim3(256), 0, stream, minbits, qn, ps, out_scores);
  hipLaunchKernelGGL(resize_kernel, dim3((NPIX + 255) / 256), dim3(256), 0, stream, ps, masks);
}